// Round 22
// baseline (256.490 us; speedup 1.0000x reference)
//
#include <hip/hip_runtime.h>

#define IN_C 256
#define HIDC 32
#define OUTC 16
#define NPB  256          // nodes per bucket (d_local = 8 bits)
#define MAXBKT 800
#define CAP  16384        // per-bucket packed capacity (mean 8184 -> 90 sigma safe)
#define EPB  12288        // edges per scatter block
#define EPT  12           // edges per thread (register cache)

typedef __attribute__((ext_vector_type(8))) short short8;
typedef __attribute__((ext_vector_type(4))) float f32x4;
union S8U4 { short8 s; unsigned u[4]; };

// ---------------- bf16 helpers ---------------------------------------------
__device__ __forceinline__ unsigned bf16pair(float a, float b) {   // RNE pack
    unsigned ua = __float_as_uint(a); ua += 0x7FFF + ((ua >> 16) & 1);
    unsigned ub = __float_as_uint(b); ub += 0x7FFF + ((ub >> 16) & 1);
    return (ua >> 16) | (ub & 0xFFFF0000u);
}
__device__ __forceinline__ float bf16lo(unsigned u) { return __uint_as_float(u << 16); }
__device__ __forceinline__ float bf16hi(unsigned u) { return __uint_as_float(u & 0xFFFF0000u); }
__device__ __forceinline__ unsigned rbf(float a) {                 // bf16 bits, RNE
    unsigned u = __float_as_uint(a);
    u += 0x7FFF + ((u >> 16) & 1);
    return u >> 16;
}
__device__ __forceinline__ void split8(const float* xf, short8& hi, short8& lo) {
    S8U4 H, L;
#pragma unroll
    for (int i = 0; i < 4; ++i) {
        float a = xf[2 * i], b = xf[2 * i + 1];
        unsigned ha = rbf(a), hb = rbf(b);
        float ra = a - __uint_as_float(ha << 16);
        float rb = b - __uint_as_float(hb << 16);
        H.u[i] = ha | (hb << 16);
        L.u[i] = rbf(ra) | (rbf(rb) << 16);
    }
    hi = H.s; lo = L.s;
}

// ---------------- edge index loaders ----------------------------------------
__device__ __forceinline__ int edge_at(const int* __restrict__ ei, long long idx, int is64) {
    return is64 ? ei[idx << 1] : ei[idx];
}
// nontemporal: edge stream is single-use — don't evict x/h1b from L2/L3
__device__ __forceinline__ int edge_at_nt(const int* __restrict__ ei, long long idx, int is64) {
    return is64 ? __builtin_nontemporal_load(ei + (idx << 1))
                : __builtin_nontemporal_load(ei + idx);
}

// ---------------- init: detect dtype + cursor init + W1 fragments ----------
__global__ void k_init(const int* __restrict__ ei, int* __restrict__ flag,
                       int* __restrict__ bkt_cur, int nbkt,
                       const float* __restrict__ W1, unsigned short* __restrict__ wf) {
    if (blockIdx.x == 0) {
        __shared__ int nz;
        if (threadIdx.x == 0) nz = 0;
        __syncthreads();
        if (ei[2 * threadIdx.x + 1] != 0) atomicOr(&nz, 1);
        for (int i = threadIdx.x; i < nbkt; i += 256) bkt_cur[i] = i * CAP;
        __syncthreads();
        if (threadIdx.x == 0) *flag = (nz == 0) ? 1 : 0;
    } else {
        int idx = (blockIdx.x - 1) * 256 + threadIdx.x;   // 0..2047
        int lane = idx & 63;
        int part = (idx >> 6) & 1;
        int tile = (idx >> 7) & 1;
        int s    = idx >> 8;
        int col = tile * 16 + (lane & 15);
        int k0  = s * 32 + (lane >> 4) * 8;
#pragma unroll
        for (int j = 0; j < 8; ++j) {
            float v = W1[(long long)(k0 + j) * HIDC + col];
            unsigned h = rbf(v);
            float r = v - __uint_as_float(h << 16);
            wf[(long long)idx * 8 + j] = (unsigned short)(part == 0 ? h : rbf(r));
        }
    }
}

// ---------------- super-kernel: edge scatter ∥ MFMA gemm1 ------------------
// Round-22: (a) gemm1 branch 2-deep x-load software pipeline (VGPR=32 showed
// the compiler serialized loads); (b) scatter uses nontemporal edge loads and
// packed stores (single-use streams; protect x/h1b cache residency).
__global__ __launch_bounds__(1024) void k_super(const int* __restrict__ ei, long long E,
                                                const int* __restrict__ flag,
                                                int* __restrict__ bkt_cur,
                                                unsigned* __restrict__ packed, int nbkt, int nsb,
                                                const float* __restrict__ x,
                                                const unsigned short* __restrict__ wf,
                                                unsigned short* __restrict__ h1b_us, int n) {
    if ((int)blockIdx.x < nsb) {
        __shared__ int hist[MAXBKT];
        int is64 = *flag;
        for (int i = threadIdx.x; i < nbkt; i += 1024) hist[i] = 0;
        __syncthreads();
        long long lo = (long long)blockIdx.x * EPB;
        int m = (int)((E - lo) < EPB ? (E - lo) : EPB);
        unsigned ew[EPT];
        int      eb[EPT];
#pragma unroll
        for (int j = 0; j < EPT; ++j) {
            int i = j * 1024 + (int)threadIdx.x;
            eb[j] = -1;
            if (i < m) {
                int s = edge_at_nt(ei, lo + i, is64);
                int d = edge_at_nt(ei, E + lo + i, is64);
                ew[j] = (unsigned)s | ((unsigned)(d & (NPB - 1)) << 20);
                eb[j] = d >> 8;
                atomicAdd(&hist[eb[j]], 1);
            }
        }
        __syncthreads();
        for (int b = threadIdx.x; b < nbkt; b += 1024) {
            int c = hist[b];
            hist[b] = c ? atomicAdd(&bkt_cur[b], c) : 0;
        }
        __syncthreads();
#pragma unroll
        for (int j = 0; j < EPT; ++j) {
            if (eb[j] >= 0) {
                int slot = atomicAdd(&hist[eb[j]], 1);
                __builtin_nontemporal_store(ew[j], &packed[slot]);
            }
        }
    } else {
        // ---- gemm1 via MFMA (unscaled output; rescale in k_bucket_csr) ----
        const int gb = (int)blockIdx.x - nsb;
        const int t = (int)threadIdx.x;
        const int l = t & 63;
        const int w = t >> 6;                                  // 0..15 waves
        const long long nb0 = (long long)gb * 256 + w * 16;
        const int kg = l >> 4;
        const long long nodeA = nb0 + (l & 15);
        const bool loadA = nodeA < n;
        const float* __restrict__ xp = x + nodeA * IN_C + kg * 8;
        f32x4 acc0 = {0.f, 0.f, 0.f, 0.f}, acc1 = {0.f, 0.f, 0.f, 0.f};
        float4 c0 = make_float4(0.f, 0.f, 0.f, 0.f);
        float4 c1 = make_float4(0.f, 0.f, 0.f, 0.f);
        if (loadA) {
            c0 = *(const float4*)(xp);
            c1 = *(const float4*)(xp + 4);
        }
#pragma unroll
        for (int s = 0; s < 8; ++s) {
            float4 n0 = make_float4(0.f, 0.f, 0.f, 0.f);
            float4 n1 = make_float4(0.f, 0.f, 0.f, 0.f);
            if (s < 7 && loadA) {                     // prefetch next k-chunk
                n0 = *(const float4*)(xp + (s + 1) * 32);
                n1 = *(const float4*)(xp + (s + 1) * 32 + 4);
            }
            float xf[8];
            xf[0] = c0.x; xf[1] = c0.y; xf[2] = c0.z; xf[3] = c0.w;
            xf[4] = c1.x; xf[5] = c1.y; xf[6] = c1.z; xf[7] = c1.w;
            short8 ah, al;
            split8(xf, ah, al);
            const unsigned short* base = wf + ((long long)(s * 4) * 64 + l) * 8;
            short8 bh0 = *(const short8*)(base);
            short8 bl0 = *(const short8*)(base + 64 * 8);
            short8 bh1 = *(const short8*)(base + 2 * 64 * 8);
            short8 bl1 = *(const short8*)(base + 3 * 64 * 8);
            acc0 = __builtin_amdgcn_mfma_f32_16x16x32_bf16(ah, bh0, acc0, 0, 0, 0);
            acc0 = __builtin_amdgcn_mfma_f32_16x16x32_bf16(ah, bl0, acc0, 0, 0, 0);
            acc0 = __builtin_amdgcn_mfma_f32_16x16x32_bf16(al, bh0, acc0, 0, 0, 0);
            acc1 = __builtin_amdgcn_mfma_f32_16x16x32_bf16(ah, bh1, acc1, 0, 0, 0);
            acc1 = __builtin_amdgcn_mfma_f32_16x16x32_bf16(ah, bl1, acc1, 0, 0, 0);
            acc1 = __builtin_amdgcn_mfma_f32_16x16x32_bf16(al, bh1, acc1, 0, 0, 0);
            c0 = n0; c1 = n1;
        }
        // D layout (m89-verified): row = (l>>4)*4 + r, col = l&15
#pragma unroll
        for (int r = 0; r < 4; ++r) {
            long long nd = nb0 + (l >> 4) * 4 + r;
            if (nd < n) {
                h1b_us[nd * 32 + (l & 15)]      = (unsigned short)rbf(acc0[r]);
                h1b_us[nd * 32 + 16 + (l & 15)] = (unsigned short)rbf(acc1[r]);
            }
        }
    }
}

// ---------------- per-bucket counting sort -> CSR + dinv + h1b rescale -----
__global__ __launch_bounds__(256) void k_bucket_csr(const unsigned* __restrict__ packed,
                                                    const int* __restrict__ bkt_cur,
                                                    int* __restrict__ csr_src,
                                                    int* __restrict__ ptr,
                                                    int* __restrict__ cnt,
                                                    float* __restrict__ dinv,
                                                    unsigned* __restrict__ h1b, int n) {
    __shared__ int hist[NPB];
    __shared__ int off[NPB];
    hist[threadIdx.x] = 0;
    __syncthreads();
    int base = blockIdx.x * CAP;
    int m = bkt_cur[blockIdx.x] - base;
    for (int i = threadIdx.x; i < m; i += 256)
        atomicAdd(&hist[packed[base + i] >> 20], 1);
    __syncthreads();
    off[threadIdx.x] = hist[threadIdx.x];
    __syncthreads();
    for (int o = 1; o < NPB; o <<= 1) {
        int v = (threadIdx.x >= o) ? off[threadIdx.x - o] : 0;
        __syncthreads();
        off[threadIdx.x] += v;
        __syncthreads();
    }
    long long node = (long long)blockIdx.x * NPB + threadIdx.x;
    {
        int exc = off[threadIdx.x] - hist[threadIdx.x];
        if (node < n) {
            float di = rsqrtf((float)hist[threadIdx.x] + 1.0f);
            ptr[node]  = base + exc;
            cnt[node]  = hist[threadIdx.x];
            dinv[node] = di;
            unsigned* row = h1b + node * 16;
#pragma unroll
            for (int q = 0; q < 16; ++q) {
                unsigned u = row[q];
                row[q] = bf16pair(bf16lo(u) * di, bf16hi(u) * di);
            }
        }
        hist[threadIdx.x] = exc;
    }
    __syncthreads();
    for (int i = threadIdx.x; i < m; i += 256) {
        unsigned w = packed[base + i];
        int r = atomicAdd(&hist[w >> 20], 1);
        csr_src[base + r] = (int)(w & 0xFFFFF);
    }
}

// ---------------- fused layer-1 aggregation + gemm2 (8B gathers) -----------
__global__ __launch_bounds__(256) void k_agg1g2(const int* __restrict__ ptr,
                                                const int* __restrict__ cnt,
                                                const int* __restrict__ csr_src,
                                                const float* __restrict__ dinv,
                                                const unsigned* __restrict__ h1b,
                                                const float* __restrict__ b1,
                                                const float* __restrict__ W2,
                                                unsigned* __restrict__ h2b, int n) {
    __shared__ float hs[32][33];
    __shared__ float wl2[32][17];
    const int t = threadIdx.x;
    for (int i = t; i < HIDC * OUTC; i += 256) wl2[i >> 4][i & 15] = W2[i];
    const int nl = t >> 3;               // 0..31 node-local
    const int qp = t & 7;                // channel quad-pair: ch 4qp..4qp+3
    const long long node = (long long)blockIdx.x * 32 + nl;
    const uint2* __restrict__ h1v = (const uint2*)h1b;   // 8 uint2 per node
    float v0 = 0.f, v1 = 0.f, v2 = 0.f, v3 = 0.f;
    if (node < n) {
        uint2 us = h1v[node * 8 + qp];
        float a0 = bf16lo(us.x), a1 = bf16hi(us.x);
        float a2 = bf16lo(us.y), a3 = bf16hi(us.y);
        int st = ptr[node], deg = cnt[node];
        int j = 0;
        for (; j + 3 < deg; j += 4) {
            int s0 = csr_src[st + j], s1 = csr_src[st + j + 1];
            int s2 = csr_src[st + j + 2], s3 = csr_src[st + j + 3];
            uint2 u0 = h1v[(long long)s0 * 8 + qp];
            uint2 u1 = h1v[(long long)s1 * 8 + qp];
            uint2 u2 = h1v[(long long)s2 * 8 + qp];
            uint2 u3 = h1v[(long long)s3 * 8 + qp];
            a0 += (bf16lo(u0.x) + bf16lo(u1.x)) + (bf16lo(u2.x) + bf16lo(u3.x));
            a1 += (bf16hi(u0.x) + bf16hi(u1.x)) + (bf16hi(u2.x) + bf16hi(u3.x));
            a2 += (bf16lo(u0.y) + bf16lo(u1.y)) + (bf16lo(u2.y) + bf16lo(u3.y));
            a3 += (bf16hi(u0.y) + bf16hi(u1.y)) + (bf16hi(u2.y) + bf16hi(u3.y));
        }
        for (; j < deg; ++j) {
            uint2 u = h1v[(long long)csr_src[st + j] * 8 + qp];
            a0 += bf16lo(u.x); a1 += bf16hi(u.x);
            a2 += bf16lo(u.y); a3 += bf16hi(u.y);
        }
        float di = dinv[node];
        v0 = a0 * di + b1[4 * qp];     v0 = v0 > 0.f ? v0 : 0.f;
        v1 = a1 * di + b1[4 * qp + 1]; v1 = v1 > 0.f ? v1 : 0.f;
        v2 = a2 * di + b1[4 * qp + 2]; v2 = v2 > 0.f ? v2 : 0.f;
        v3 = a3 * di + b1[4 * qp + 3]; v3 = v3 > 0.f ? v3 : 0.f;
    }
    hs[nl][4 * qp]     = v0;
    hs[nl][4 * qp + 1] = v1;
    hs[nl][4 * qp + 2] = v2;
    hs[nl][4 * qp + 3] = v3;
    __syncthreads();
    {
        int nl2 = t >> 3;                // 32 nodes
        int op  = t & 7;                 // 8 output pairs
        long long nd = (long long)blockIdx.x * 32 + nl2;
        if (nd < n) {
            float o0 = 0.f, o1 = 0.f;
#pragma unroll
            for (int k = 0; k < HIDC; ++k) {
                float h = hs[nl2][k];
                o0 = fmaf(h, wl2[k][2 * op],     o0);
                o1 = fmaf(h, wl2[k][2 * op + 1], o1);
            }
            float di = dinv[nd];
            h2b[nd * 8 + op] = bf16pair(o0 * di, o1 * di);
        }
    }
}

// ---------------- layer-2 pull aggregation (8B gathers) -> d_out -----------
__global__ __launch_bounds__(256) void k_agg2csr(const int* __restrict__ ptr,
                                                 const int* __restrict__ cnt,
                                                 const int* __restrict__ csr_src,
                                                 const float* __restrict__ dinv,
                                                 const unsigned* __restrict__ h2b,
                                                 const float* __restrict__ b2,
                                                 float* __restrict__ out, int n) {
    long long g = (long long)blockIdx.x * blockDim.x + threadIdx.x;
    int node = (int)(g >> 2);
    int qp = (int)(g & 3);               // ch 4qp..4qp+3
    if (node >= n) return;
    const uint2* __restrict__ h2v = (const uint2*)h2b;   // 4 uint2 per node
    uint2 us = h2v[(long long)node * 4 + qp];
    float a0 = bf16lo(us.x), a1 = bf16hi(us.x);
    float a2 = bf16lo(us.y), a3 = bf16hi(us.y);
    int st = ptr[node], deg = cnt[node];
    int j = 0;
    for (; j + 3 < deg; j += 4) {
        int s0 = csr_src[st + j], s1 = csr_src[st + j + 1];
        int s2 = csr_src[st + j + 2], s3 = csr_src[st + j + 3];
        uint2 u0 = h2v[(long long)s0 * 4 + qp];
        uint2 u1 = h2v[(long long)s1 * 4 + qp];
        uint2 u2 = h2v[(long long)s2 * 4 + qp];
        uint2 u3 = h2v[(long long)s3 * 4 + qp];
        a0 += (bf16lo(u0.x) + bf16lo(u1.x)) + (bf16lo(u2.x) + bf16lo(u3.x));
        a1 += (bf16hi(u0.x) + bf16hi(u1.x)) + (bf16hi(u2.x) + bf16hi(u3.x));
        a2 += (bf16lo(u0.y) + bf16lo(u1.y)) + (bf16lo(u2.y) + bf16lo(u3.y));
        a3 += (bf16hi(u0.y) + bf16hi(u1.y)) + (bf16hi(u2.y) + bf16hi(u3.y));
    }
    for (; j < deg; ++j) {
        uint2 u = h2v[(long long)csr_src[st + j] * 4 + qp];
        a0 += bf16lo(u.x); a1 += bf16hi(u.x);
        a2 += bf16lo(u.y); a3 += bf16hi(u.y);
    }
    float di = dinv[node];
    *(float4*)(out + (long long)node * OUTC + 4 * qp) =
        make_float4(a0 * di + b2[4 * qp],     a1 * di + b2[4 * qp + 1],
                    a2 * di + b2[4 * qp + 2], a3 * di + b2[4 * qp + 3]);
}

extern "C" void kernel_launch(void* const* d_in, const int* in_sizes, int n_in,
                              void* d_out, int out_size, void* d_ws, size_t ws_size,
                              hipStream_t stream) {
    const float* x  = (const float*)d_in[0];
    const int*   ei = (const int*)d_in[1];
    const float* W1 = (const float*)d_in[2];
    const float* b1 = (const float*)d_in[3];
    const float* W2 = (const float*)d_in[4];
    const float* b2 = (const float*)d_in[5];
    const int n = in_sizes[0] / IN_C;            // 100000
    const long long E = in_sizes[1] / 2;         // 3200000
    float* out = (float*)d_out;

    const int nbkt = (n + NPB - 1) / NPB;        // 391
    const int nsb  = (int)((E + EPB - 1) / EPB); // 261 scatter blocks
    const int ngb  = (n + 255) / 256;            // 391 gemm1 blocks

    char* ws = (char*)d_ws;
    size_t off = 0;
    auto alloc = [&](size_t bytes) { void* p = ws + off; off += (bytes + 255) & ~(size_t)255; return p; };
    int*      flag     = (int*)alloc(256);
    int*      bkt_cur  = (int*)alloc((size_t)MAXBKT * 4);
    float*    dinv     = (float*)alloc((size_t)n * 4);
    int*      cnt      = (int*)alloc((size_t)n * 4);
    int*      ptr      = (int*)alloc((size_t)n * 4);
    unsigned* packed   = (unsigned*)alloc((size_t)nbkt * CAP * 4);        // 25.6 MB
    int*      csr_src  = (int*)alloc((size_t)nbkt * CAP * 4);             // 25.6 MB
    unsigned short* wf = (unsigned short*)alloc(8 * 2 * 2 * 64 * 8 * 2);  // 32 KB
    unsigned* h1b      = (unsigned*)alloc((size_t)n * (HIDC / 2) * 4);    // bf16 [n][32]
    unsigned* h2b      = (unsigned*)alloc((size_t)n * (OUTC / 2) * 4);    // bf16 [n][16]

    k_init<<<9, 256, 0, stream>>>(ei, flag, bkt_cur, nbkt, W1, wf);
    k_super<<<nsb + ngb, 1024, 0, stream>>>(ei, E, flag, bkt_cur, packed, nbkt, nsb,
                                            x, wf, (unsigned short*)h1b, n);
    k_bucket_csr<<<nbkt, NPB, 0, stream>>>(packed, bkt_cur, csr_src, ptr, cnt, dinv, h1b, n);
    k_agg1g2<<<(n + 31) / 32, 256, 0, stream>>>(ptr, cnt, csr_src, dinv, h1b, b1, W2, h2b, n);
    k_agg2csr<<<(int)(((long long)n * 4 + 255) / 256), 256, 0, stream>>>(
        ptr, cnt, csr_src, dinv, h2b, b2, out, n);
}

// Round 23
// 159.166 us; speedup vs baseline: 1.6115x; 1.6115x over previous
//
#include <hip/hip_runtime.h>

#define IN_C 256
#define HIDC 32
#define OUTC 16
#define NPB  256          // nodes per bucket (d_local = 8 bits)
#define MAXBKT 800
#define CAP  16384        // per-bucket packed capacity (mean 8184 -> 90 sigma safe)
#define EPB  12288        // edges per scatter block
#define EPT  12           // edges per thread (register cache)

typedef __attribute__((ext_vector_type(8))) short short8;
typedef __attribute__((ext_vector_type(4))) float f32x4;
union S8U4 { short8 s; unsigned u[4]; };

// ---------------- bf16 helpers ---------------------------------------------
__device__ __forceinline__ unsigned bf16pair(float a, float b) {   // RNE pack
    unsigned ua = __float_as_uint(a); ua += 0x7FFF + ((ua >> 16) & 1);
    unsigned ub = __float_as_uint(b); ub += 0x7FFF + ((ub >> 16) & 1);
    return (ua >> 16) | (ub & 0xFFFF0000u);
}
__device__ __forceinline__ float bf16lo(unsigned u) { return __uint_as_float(u << 16); }
__device__ __forceinline__ float bf16hi(unsigned u) { return __uint_as_float(u & 0xFFFF0000u); }
__device__ __forceinline__ unsigned rbf(float a) {                 // bf16 bits, RNE
    unsigned u = __float_as_uint(a);
    u += 0x7FFF + ((u >> 16) & 1);
    return u >> 16;
}
__device__ __forceinline__ void split8(const float* xf, short8& hi, short8& lo) {
    S8U4 H, L;
#pragma unroll
    for (int i = 0; i < 4; ++i) {
        float a = xf[2 * i], b = xf[2 * i + 1];
        unsigned ha = rbf(a), hb = rbf(b);
        float ra = a - __uint_as_float(ha << 16);
        float rb = b - __uint_as_float(hb << 16);
        H.u[i] = ha | (hb << 16);
        L.u[i] = rbf(ra) | (rbf(rb) << 16);
    }
    hi = H.s; lo = L.s;
}

// ---------------- edge index loader (handles int32 or int64 storage) -------
__device__ __forceinline__ int edge_at(const int* __restrict__ ei, long long idx, int is64) {
    return is64 ? ei[idx << 1] : ei[idx];
}

// ---------------- init: detect dtype + cursor init + W1 fragments ----------
__global__ void k_init(const int* __restrict__ ei, int* __restrict__ flag,
                       int* __restrict__ bkt_cur, int nbkt,
                       const float* __restrict__ W1, unsigned short* __restrict__ wf) {
    if (blockIdx.x == 0) {
        __shared__ int nz;
        if (threadIdx.x == 0) nz = 0;
        __syncthreads();
        if (ei[2 * threadIdx.x + 1] != 0) atomicOr(&nz, 1);
        for (int i = threadIdx.x; i < nbkt; i += 256) bkt_cur[i] = i * CAP;
        __syncthreads();
        if (threadIdx.x == 0) *flag = (nz == 0) ? 1 : 0;
    } else {
        int idx = (blockIdx.x - 1) * 256 + threadIdx.x;   // 0..2047
        int lane = idx & 63;
        int part = (idx >> 6) & 1;
        int tile = (idx >> 7) & 1;
        int s    = idx >> 8;
        int col = tile * 16 + (lane & 15);
        int k0  = s * 32 + (lane >> 4) * 8;
#pragma unroll
        for (int j = 0; j < 8; ++j) {
            float v = W1[(long long)(k0 + j) * HIDC + col];
            unsigned h = rbf(v);
            float r = v - __uint_as_float(h << 16);
            wf[(long long)idx * 8 + j] = (unsigned short)(part == 0 ? h : rbf(r));
        }
    }
}

// ---------------- super-kernel: edge scatter ∥ MFMA gemm1 (round-19/21) ----
// Round-22 lesson: nontemporal stores on SCATTERED 4B writes tripled
// WRITE_SIZE (no L2 write-combining) — regular stores restored.
__global__ __launch_bounds__(1024) void k_super(const int* __restrict__ ei, long long E,
                                                const int* __restrict__ flag,
                                                int* __restrict__ bkt_cur,
                                                unsigned* __restrict__ packed, int nbkt, int nsb,
                                                const float* __restrict__ x,
                                                const unsigned short* __restrict__ wf,
                                                unsigned short* __restrict__ h1b_us, int n) {
    if ((int)blockIdx.x < nsb) {
        __shared__ int hist[MAXBKT];
        int is64 = *flag;
        for (int i = threadIdx.x; i < nbkt; i += 1024) hist[i] = 0;
        __syncthreads();
        long long lo = (long long)blockIdx.x * EPB;
        int m = (int)((E - lo) < EPB ? (E - lo) : EPB);
        unsigned ew[EPT];
        int      eb[EPT];
#pragma unroll
        for (int j = 0; j < EPT; ++j) {
            int i = j * 1024 + (int)threadIdx.x;
            eb[j] = -1;
            if (i < m) {
                int s = edge_at(ei, lo + i, is64);
                int d = edge_at(ei, E + lo + i, is64);
                ew[j] = (unsigned)s | ((unsigned)(d & (NPB - 1)) << 20);
                eb[j] = d >> 8;
                atomicAdd(&hist[eb[j]], 1);
            }
        }
        __syncthreads();
        for (int b = threadIdx.x; b < nbkt; b += 1024) {
            int c = hist[b];
            hist[b] = c ? atomicAdd(&bkt_cur[b], c) : 0;
        }
        __syncthreads();
#pragma unroll
        for (int j = 0; j < EPT; ++j) {
            if (eb[j] >= 0) {
                int slot = atomicAdd(&hist[eb[j]], 1);
                packed[slot] = ew[j];
            }
        }
    } else {
        // ---- gemm1 via MFMA (unscaled output; rescale in k_bucket_csr) ----
        const int gb = (int)blockIdx.x - nsb;
        const int t = (int)threadIdx.x;
        const int l = t & 63;
        const int w = t >> 6;                                  // 0..15 waves
        const long long nb0 = (long long)gb * 256 + w * 16;
        const int kg = l >> 4;
        const long long nodeA = nb0 + (l & 15);
        const bool loadA = nodeA < n;
        f32x4 acc0 = {0.f, 0.f, 0.f, 0.f}, acc1 = {0.f, 0.f, 0.f, 0.f};
#pragma unroll
        for (int s = 0; s < 8; ++s) {
            float xf[8];
            if (loadA) {
                float4 v0 = *(const float4*)(x + nodeA * IN_C + s * 32 + kg * 8);
                float4 v1 = *(const float4*)(x + nodeA * IN_C + s * 32 + kg * 8 + 4);
                xf[0] = v0.x; xf[1] = v0.y; xf[2] = v0.z; xf[3] = v0.w;
                xf[4] = v1.x; xf[5] = v1.y; xf[6] = v1.z; xf[7] = v1.w;
            } else {
#pragma unroll
                for (int j = 0; j < 8; ++j) xf[j] = 0.f;
            }
            short8 ah, al;
            split8(xf, ah, al);
            const unsigned short* base = wf + ((long long)(s * 4) * 64 + l) * 8;
            short8 bh0 = *(const short8*)(base);
            short8 bl0 = *(const short8*)(base + 64 * 8);
            short8 bh1 = *(const short8*)(base + 2 * 64 * 8);
            short8 bl1 = *(const short8*)(base + 3 * 64 * 8);
            acc0 = __builtin_amdgcn_mfma_f32_16x16x32_bf16(ah, bh0, acc0, 0, 0, 0);
            acc0 = __builtin_amdgcn_mfma_f32_16x16x32_bf16(ah, bl0, acc0, 0, 0, 0);
            acc0 = __builtin_amdgcn_mfma_f32_16x16x32_bf16(al, bh0, acc0, 0, 0, 0);
            acc1 = __builtin_amdgcn_mfma_f32_16x16x32_bf16(ah, bh1, acc1, 0, 0, 0);
            acc1 = __builtin_amdgcn_mfma_f32_16x16x32_bf16(ah, bl1, acc1, 0, 0, 0);
            acc1 = __builtin_amdgcn_mfma_f32_16x16x32_bf16(al, bh1, acc1, 0, 0, 0);
        }
        // D layout (m89-verified): row = (l>>4)*4 + r, col = l&15
#pragma unroll
        for (int r = 0; r < 4; ++r) {
            long long nd = nb0 + (l >> 4) * 4 + r;
            if (nd < n) {
                h1b_us[nd * 32 + (l & 15)]      = (unsigned short)rbf(acc0[r]);
                h1b_us[nd * 32 + 16 + (l & 15)] = (unsigned short)rbf(acc1[r]);
            }
        }
    }
}

// ---------------- per-bucket counting sort -> CSR + dinv + h1b rescale -----
__global__ __launch_bounds__(256) void k_bucket_csr(const unsigned* __restrict__ packed,
                                                    const int* __restrict__ bkt_cur,
                                                    int* __restrict__ csr_src,
                                                    int* __restrict__ ptr,
                                                    int* __restrict__ cnt,
                                                    float* __restrict__ dinv,
                                                    unsigned* __restrict__ h1b, int n) {
    __shared__ int hist[NPB];
    __shared__ int off[NPB];
    hist[threadIdx.x] = 0;
    __syncthreads();
    int base = blockIdx.x * CAP;
    int m = bkt_cur[blockIdx.x] - base;
    for (int i = threadIdx.x; i < m; i += 256)
        atomicAdd(&hist[packed[base + i] >> 20], 1);
    __syncthreads();
    off[threadIdx.x] = hist[threadIdx.x];
    __syncthreads();
    for (int o = 1; o < NPB; o <<= 1) {
        int v = (threadIdx.x >= o) ? off[threadIdx.x - o] : 0;
        __syncthreads();
        off[threadIdx.x] += v;
        __syncthreads();
    }
    long long node = (long long)blockIdx.x * NPB + threadIdx.x;
    {
        int exc = off[threadIdx.x] - hist[threadIdx.x];
        if (node < n) {
            float di = rsqrtf((float)hist[threadIdx.x] + 1.0f);
            ptr[node]  = base + exc;
            cnt[node]  = hist[threadIdx.x];
            dinv[node] = di;
            // rescale unscaled gemm1 output: h1b[node] *= di (bf16 in, bf16 out)
            unsigned* row = h1b + node * 16;
#pragma unroll
            for (int q = 0; q < 16; ++q) {
                unsigned u = row[q];
                row[q] = bf16pair(bf16lo(u) * di, bf16hi(u) * di);
            }
        }
        hist[threadIdx.x] = exc;
    }
    __syncthreads();
    for (int i = threadIdx.x; i < m; i += 256) {
        unsigned w = packed[base + i];
        int r = atomicAdd(&hist[w >> 20], 1);
        csr_src[base + r] = (int)(w & 0xFFFFF);
    }
}

// ---------------- fused layer-1 aggregation + gemm2 (8B gathers) -----------
__global__ __launch_bounds__(256) void k_agg1g2(const int* __restrict__ ptr,
                                                const int* __restrict__ cnt,
                                                const int* __restrict__ csr_src,
                                                const float* __restrict__ dinv,
                                                const unsigned* __restrict__ h1b,
                                                const float* __restrict__ b1,
                                                const float* __restrict__ W2,
                                                unsigned* __restrict__ h2b, int n) {
    __shared__ float hs[32][33];
    __shared__ float wl2[32][17];
    const int t = threadIdx.x;
    for (int i = t; i < HIDC * OUTC; i += 256) wl2[i >> 4][i & 15] = W2[i];
    const int nl = t >> 3;               // 0..31 node-local
    const int qp = t & 7;                // channel quad-pair: ch 4qp..4qp+3
    const long long node = (long long)blockIdx.x * 32 + nl;
    const uint2* __restrict__ h1v = (const uint2*)h1b;   // 8 uint2 per node
    float v0 = 0.f, v1 = 0.f, v2 = 0.f, v3 = 0.f;
    if (node < n) {
        uint2 us = h1v[node * 8 + qp];
        float a0 = bf16lo(us.x), a1 = bf16hi(us.x);
        float a2 = bf16lo(us.y), a3 = bf16hi(us.y);
        int st = ptr[node], deg = cnt[node];
        int j = 0;
        for (; j + 3 < deg; j += 4) {
            int s0 = csr_src[st + j], s1 = csr_src[st + j + 1];
            int s2 = csr_src[st + j + 2], s3 = csr_src[st + j + 3];
            uint2 u0 = h1v[(long long)s0 * 8 + qp];
            uint2 u1 = h1v[(long long)s1 * 8 + qp];
            uint2 u2 = h1v[(long long)s2 * 8 + qp];
            uint2 u3 = h1v[(long long)s3 * 8 + qp];
            a0 += (bf16lo(u0.x) + bf16lo(u1.x)) + (bf16lo(u2.x) + bf16lo(u3.x));
            a1 += (bf16hi(u0.x) + bf16hi(u1.x)) + (bf16hi(u2.x) + bf16hi(u3.x));
            a2 += (bf16lo(u0.y) + bf16lo(u1.y)) + (bf16lo(u2.y) + bf16lo(u3.y));
            a3 += (bf16hi(u0.y) + bf16hi(u1.y)) + (bf16hi(u2.y) + bf16hi(u3.y));
        }
        for (; j < deg; ++j) {
            uint2 u = h1v[(long long)csr_src[st + j] * 8 + qp];
            a0 += bf16lo(u.x); a1 += bf16hi(u.x);
            a2 += bf16lo(u.y); a3 += bf16hi(u.y);
        }
        float di = dinv[node];
        v0 = a0 * di + b1[4 * qp];     v0 = v0 > 0.f ? v0 : 0.f;
        v1 = a1 * di + b1[4 * qp + 1]; v1 = v1 > 0.f ? v1 : 0.f;
        v2 = a2 * di + b1[4 * qp + 2]; v2 = v2 > 0.f ? v2 : 0.f;
        v3 = a3 * di + b1[4 * qp + 3]; v3 = v3 > 0.f ? v3 : 0.f;
    }
    hs[nl][4 * qp]     = v0;
    hs[nl][4 * qp + 1] = v1;
    hs[nl][4 * qp + 2] = v2;
    hs[nl][4 * qp + 3] = v3;
    __syncthreads();
    {
        int nl2 = t >> 3;                // 32 nodes
        int op  = t & 7;                 // 8 output pairs
        long long nd = (long long)blockIdx.x * 32 + nl2;
        if (nd < n) {
            float o0 = 0.f, o1 = 0.f;
#pragma unroll
            for (int k = 0; k < HIDC; ++k) {
                float h = hs[nl2][k];
                o0 = fmaf(h, wl2[k][2 * op],     o0);
                o1 = fmaf(h, wl2[k][2 * op + 1], o1);
            }
            float di = dinv[nd];
            h2b[nd * 8 + op] = bf16pair(o0 * di, o1 * di);
        }
    }
}

// ---------------- layer-2 pull aggregation (8B gathers) -> d_out -----------
__global__ __launch_bounds__(256) void k_agg2csr(const int* __restrict__ ptr,
                                                 const int* __restrict__ cnt,
                                                 const int* __restrict__ csr_src,
                                                 const float* __restrict__ dinv,
                                                 const unsigned* __restrict__ h2b,
                                                 const float* __restrict__ b2,
                                                 float* __restrict__ out, int n) {
    long long g = (long long)blockIdx.x * blockDim.x + threadIdx.x;
    int node = (int)(g >> 2);
    int qp = (int)(g & 3);               // ch 4qp..4qp+3
    if (node >= n) return;
    const uint2* __restrict__ h2v = (const uint2*)h2b;   // 4 uint2 per node
    uint2 us = h2v[(long long)node * 4 + qp];
    float a0 = bf16lo(us.x), a1 = bf16hi(us.x);
    float a2 = bf16lo(us.y), a3 = bf16hi(us.y);
    int st = ptr[node], deg = cnt[node];
    int j = 0;
    for (; j + 3 < deg; j += 4) {
        int s0 = csr_src[st + j], s1 = csr_src[st + j + 1];
        int s2 = csr_src[st + j + 2], s3 = csr_src[st + j + 3];
        uint2 u0 = h2v[(long long)s0 * 4 + qp];
        uint2 u1 = h2v[(long long)s1 * 4 + qp];
        uint2 u2 = h2v[(long long)s2 * 4 + qp];
        uint2 u3 = h2v[(long long)s3 * 4 + qp];
        a0 += (bf16lo(u0.x) + bf16lo(u1.x)) + (bf16lo(u2.x) + bf16lo(u3.x));
        a1 += (bf16hi(u0.x) + bf16hi(u1.x)) + (bf16hi(u2.x) + bf16hi(u3.x));
        a2 += (bf16lo(u0.y) + bf16lo(u1.y)) + (bf16lo(u2.y) + bf16lo(u3.y));
        a3 += (bf16hi(u0.y) + bf16hi(u1.y)) + (bf16hi(u2.y) + bf16hi(u3.y));
    }
    for (; j < deg; ++j) {
        uint2 u = h2v[(long long)csr_src[st + j] * 4 + qp];
        a0 += bf16lo(u.x); a1 += bf16hi(u.x);
        a2 += bf16lo(u.y); a3 += bf16hi(u.y);
    }
    float di = dinv[node];
    *(float4*)(out + (long long)node * OUTC + 4 * qp) =
        make_float4(a0 * di + b2[4 * qp],     a1 * di + b2[4 * qp + 1],
                    a2 * di + b2[4 * qp + 2], a3 * di + b2[4 * qp + 3]);
}

extern "C" void kernel_launch(void* const* d_in, const int* in_sizes, int n_in,
                              void* d_out, int out_size, void* d_ws, size_t ws_size,
                              hipStream_t stream) {
    const float* x  = (const float*)d_in[0];
    const int*   ei = (const int*)d_in[1];
    const float* W1 = (const float*)d_in[2];
    const float* b1 = (const float*)d_in[3];
    const float* W2 = (const float*)d_in[4];
    const float* b2 = (const float*)d_in[5];
    const int n = in_sizes[0] / IN_C;            // 100000
    const long long E = in_sizes[1] / 2;         // 3200000
    float* out = (float*)d_out;

    const int nbkt = (n + NPB - 1) / NPB;        // 391
    const int nsb  = (int)((E + EPB - 1) / EPB); // 261 scatter blocks
    const int ngb  = (n + 255) / 256;            // 391 gemm1 blocks

    char* ws = (char*)d_ws;
    size_t off = 0;
    auto alloc = [&](size_t bytes) { void* p = ws + off; off += (bytes + 255) & ~(size_t)255; return p; };
    int*      flag     = (int*)alloc(256);
    int*      bkt_cur  = (int*)alloc((size_t)MAXBKT * 4);
    float*    dinv     = (float*)alloc((size_t)n * 4);
    int*      cnt      = (int*)alloc((size_t)n * 4);
    int*      ptr      = (int*)alloc((size_t)n * 4);
    unsigned* packed   = (unsigned*)alloc((size_t)nbkt * CAP * 4);        // 25.6 MB
    int*      csr_src  = (int*)alloc((size_t)nbkt * CAP * 4);             // 25.6 MB
    unsigned short* wf = (unsigned short*)alloc(8 * 2 * 2 * 64 * 8 * 2);  // 32 KB
    unsigned* h1b      = (unsigned*)alloc((size_t)n * (HIDC / 2) * 4);    // bf16 [n][32]
    unsigned* h2b      = (unsigned*)alloc((size_t)n * (OUTC / 2) * 4);    // bf16 [n][16]

    k_init<<<9, 256, 0, stream>>>(ei, flag, bkt_cur, nbkt, W1, wf);
    k_super<<<nsb + ngb, 1024, 0, stream>>>(ei, E, flag, bkt_cur, packed, nbkt, nsb,
                                            x, wf, (unsigned short*)h1b, n);
    k_bucket_csr<<<nbkt, NPB, 0, stream>>>(packed, bkt_cur, csr_src, ptr, cnt, dinv, h1b, n);
    k_agg1g2<<<(n + 31) / 32, 256, 0, stream>>>(ptr, cnt, csr_src, dinv, h1b, b1, W2, h2b, n);
    k_agg2csr<<<(int)(((long long)n * 4 + 255) / 256), 256, 0, stream>>>(
        ptr, cnt, csr_src, dinv, h2b, b2, out, n);
}